// Round 5
// baseline (179.098 us; speedup 1.0000x reference)
//
#include <hip/hip_runtime.h>
#include <math.h>

namespace {

constexpr int Bb = 16;
constexpr int Ll = 1024;
constexpr int Dd = 512;
constexpr int TOPK = 6;
constexpr int Kc = 512;          // K dim of every GEMM
constexpr int NT = Kc / 32;      // 16 K-tiles of BK=32

typedef short  short8 __attribute__((ext_vector_type(8)));
typedef float  f32x4  __attribute__((ext_vector_type(4)));

__device__ __forceinline__ short f2bf(float x) {
  unsigned u = __builtin_bit_cast(unsigned, x);
  u += 0x7fffu + ((u >> 16) & 1u);          // RNE
  return (short)(u >> 16);
}
__device__ __forceinline__ float bf2f(short b) {
  unsigned u = ((unsigned)(unsigned short)b) << 16;
  return __builtin_bit_cast(float, u);
}
__device__ __forceinline__ void g2l16(const void* g, void* l) {
  __builtin_amdgcn_global_load_lds(
      (const __attribute__((address_space(1))) unsigned*)g,
      (__attribute__((address_space(3))) unsigned*)l, 16, 0, 0);
}
__device__ __forceinline__ short8 cvt8(float4 a, float4 b) {
  short8 o;
  o[0] = f2bf(a.x); o[1] = f2bf(a.y); o[2] = f2bf(a.z); o[3] = f2bf(a.w);
  o[4] = f2bf(b.x); o[5] = f2bf(b.y); o[6] = f2bf(b.z); o[7] = f2bf(b.w);
  return o;
}

#define BARRIER() do { asm volatile("" ::: "memory"); \
    __builtin_amdgcn_s_barrier(); \
    asm volatile("" ::: "memory"); } while (0)
#define VMCNT3() asm volatile("s_waitcnt vmcnt(3)" ::: "memory")
#define VMCNT1() asm volatile("s_waitcnt vmcnt(1)" ::: "memory")
#define VMCNT0() asm volatile("s_waitcnt vmcnt(0)" ::: "memory")
#define LGKM0()  do { asm volatile("s_waitcnt lgkmcnt(0)" ::: "memory"); \
    __builtin_amdgcn_sched_barrier(0); } while (0)

// ===========================================================================
// Ring-pipelined NT GEMM: C[m][n] = sum_k A[m][k]*BT[n][k].  BM=256 BN=128
// BK=32; 8 waves (4Mx2N) of 64x64; 3-slot LDS ring; counted vmcnt; swizzled
// LDS; setprio.  N == K == 512 for all modes.
// MODE 0: z=0/1: A fp32 reg-staged+cvt, BT bf16, C bf16 (LDS-staged stores)
//         z=2  : pure fp32->bf16 copy (Av -> Cv), no GEMM
// MODE 1: corr: A,B bf16 (batch z); fused circular-diagonal reduce into mv[z]
// MODE 2: fc  : A,B bf16; C fp32 (LDS-staged stores)
// ===========================================================================
template<int MODE>
__global__ __launch_bounds__(512) void gemm_ring(
    const void* __restrict__ Aq, const void* __restrict__ Ak,
    const void* __restrict__ Av,
    const short* __restrict__ Bq, const short* __restrict__ Bk,
    const short* __restrict__ Bv,
    void* __restrict__ Cq, void* __restrict__ Ck, void* __restrict__ Cv)
{
  __shared__ short lds3[3][12288];       // slots; reused as epilogue buffer
  __shared__ float bins[384];

  const int tid = threadIdx.x;
  const int z   = blockIdx.z;

  // ---- MODE 0 / z==2: straight fp32->bf16 copy of K input ----
  if (MODE == 0 && z == 2) {
    const float* src = (const float*)Av;
    short* dst = (short*)Cv;
    const int base = blockIdx.x * 512 + tid;          // 131072 threads
#pragma unroll
    for (int it = 0; it < 8; ++it) {
      const size_t li = (size_t)(base + it * 131072) * 8;
      const float4 a = *(const float4*)(src + li);
      const float4 b = *(const float4*)(src + li + 4);
      *(short8*)&dst[li] = cvt8(a, b);
    }
    return;
  }

  // ---- block tile coords (bijective XCD swizzle; gridDim.x % 8 == 0) ----
  int m0, n0;
  {
    const int fb = blockIdx.x;
    if (MODE == 1) {
      const int s = (fb & 7) * 4 + (fb >> 3);          // 32 blocks/batch
      m0 = (s >> 3) * 256;  n0 = (s & 7) * 128;        // 4 x 8 tiles
    } else {
      const int chunk = gridDim.x >> 3;
      const int s = (fb & 7) * chunk + (fb >> 3);
      m0 = (s >> 2) * 256;  n0 = (s & 3) * 128;        // M/256 x 4 tiles
    }
  }

  // ---- operand base pointers ----
  const float* Af = nullptr;
  const short* Ab = nullptr;
  const short* Bp;
  if (MODE == 0) {
    Af = (const float*)((z == 0) ? Aq : Ak);
    Bp = (z == 0) ? Bq : Bk;
  } else if (MODE == 1) {
    Ab = (const short*)Aq + (size_t)z * Ll * Kc;
    Bp = Bq + (size_t)z * Ll * Kc;
  } else {
    Ab = (const short*)Aq;
    Bp = Bq;
  }

  // ---- staging maps (swizzle: unit = row*4 + (c8 ^ ((row>>1)&3))) ----
  const int rB  = tid >> 2;
  const int c8B = (tid & 3) ^ ((rB >> 1) & 3);
  const short* gB = Bp + (size_t)(n0 + rB) * Kc + c8B * 8;
  const int destB = 8192 + tid * 8;

  const int rA  = tid >> 2;
  const int c8A = (tid & 3) ^ ((rA >> 1) & 3);
  const short* gA0 = nullptr; const short* gA1 = nullptr;
  if (MODE != 0) {
    gA0 = Ab + (size_t)(m0 + rA) * Kc + c8A * 8;
    gA1 = gA0 + (size_t)128 * Kc;
  }
  const int destA0 = tid * 8, destA1 = tid * 8 + 4096;

  const int rP  = tid >> 1;
  const int c8P = 2 * (tid & 1);
  const float* gAf = nullptr;
  int uW0 = 0, uW1 = 0;
  if (MODE == 0) {
    gAf = Af + (size_t)(m0 + rP) * Kc + c8P * 8;
    uW0 = rP * 4 + (c8P ^ ((rP >> 1) & 3));
    uW1 = uW0 ^ 1;
  }

  // ---- fragment read offsets ----
  const int lane = tid & 63;
  const int wid  = tid >> 6;
  const int wr = wid >> 1, wn = wid & 1;
  const int lo = lane & 15, hi = lane >> 4;
  int aoff[4], boff[4];
#pragma unroll
  for (int i = 0; i < 4; ++i) {
    const int ar = wr * 64 + i * 16 + lo;
    aoff[i] = (ar * 4 + (hi ^ ((ar >> 1) & 3))) * 8;
  }
#pragma unroll
  for (int j = 0; j < 4; ++j) {
    const int br = wn * 64 + j * 16 + lo;
    boff[j] = 8192 + (br * 4 + (hi ^ ((br >> 1) & 3))) * 8;
  }

  if (MODE == 1 && tid < 384) bins[tid] = 0.f;

  f32x4 acc[4][4];
#pragma unroll
  for (int i = 0; i < 4; ++i)
#pragma unroll
    for (int j = 0; j < 4; ++j) acc[i][j] = (f32x4){0.f, 0.f, 0.f, 0.f};

  // ---- prologue: stage tiles 0 -> slot0, 1 -> slot1 ----
  if (MODE == 0) {
    float4 p0 = *(const float4*)(gAf + 0);
    float4 p1 = *(const float4*)(gAf + 4);
    float4 p2 = *(const float4*)(gAf + 8);
    float4 p3 = *(const float4*)(gAf + 12);
    g2l16(gB, &lds3[0][destB]);
    float4 q0 = *(const float4*)(gAf + 32);
    float4 q1 = *(const float4*)(gAf + 36);
    float4 q2 = *(const float4*)(gAf + 40);
    float4 q3 = *(const float4*)(gAf + 44);
    g2l16(gB + 32, &lds3[1][destB]);
    *(short8*)&lds3[0][uW0 * 8] = cvt8(p0, p1);
    *(short8*)&lds3[0][uW1 * 8] = cvt8(p2, p3);
    *(short8*)&lds3[1][uW0 * 8] = cvt8(q0, q1);
    *(short8*)&lds3[1][uW1 * 8] = cvt8(q2, q3);
    LGKM0();
    VMCNT1();
  } else {
    g2l16(gA0,      &lds3[0][destA0]);
    g2l16(gA1,      &lds3[0][destA1]);
    g2l16(gB,       &lds3[0][destB]);
    g2l16(gA0 + 32, &lds3[1][destA0]);
    g2l16(gA1 + 32, &lds3[1][destA1]);
    g2l16(gB  + 32, &lds3[1][destB]);
    VMCNT3();
  }
  BARRIER();

  // ---- main 16-phase pipeline ----
  int sr = 0, sw = 2;
#pragma unroll 1
  for (int t = 0; t < NT; ++t) {
    const short* L = &lds3[sr][0];
    short8 af[4], bfr[4];
#pragma unroll
    for (int i = 0; i < 4; ++i) af[i]  = *(const short8*)(L + aoff[i]);
#pragma unroll
    for (int j = 0; j < 4; ++j) bfr[j] = *(const short8*)(L + boff[j]);

    float4 s0, s1, s2, s3;
    if (t < NT - 2) {
      const int ke = (t + 2) * 32;
      if (MODE == 0) {
        s0 = *(const float4*)(gAf + ke + 0);
        s1 = *(const float4*)(gAf + ke + 4);
        s2 = *(const float4*)(gAf + ke + 8);
        s3 = *(const float4*)(gAf + ke + 12);
        g2l16(gB + ke, &lds3[sw][destB]);
      } else {
        g2l16(gA0 + ke, &lds3[sw][destA0]);
        g2l16(gA1 + ke, &lds3[sw][destA1]);
        g2l16(gB  + ke, &lds3[sw][destB]);
      }
    }

    BARRIER();
    __builtin_amdgcn_s_setprio(1);
#pragma unroll
    for (int i = 0; i < 4; ++i)
#pragma unroll
      for (int j = 0; j < 4; ++j)
        acc[i][j] = __builtin_amdgcn_mfma_f32_16x16x32_bf16(af[i], bfr[j], acc[i][j], 0, 0, 0);
    __builtin_amdgcn_s_setprio(0);

    if (MODE == 0) {
      if (t < NT - 2) {
        *(short8*)&lds3[sw][uW0 * 8] = cvt8(s0, s1);
        *(short8*)&lds3[sw][uW1 * 8] = cvt8(s2, s3);
        LGKM0();
        VMCNT1();
      } else if (t == NT - 2) {
        VMCNT0();
      }
    } else {
      if (t < NT - 2)       VMCNT3();
      else if (t == NT - 2) VMCNT0();
    }
    BARRIER();
    sr = (sr == 2) ? 0 : sr + 1;
    sw = (sw == 2) ? 0 : sw + 1;
  }

  // ---- epilogue ----
  if (MODE == 0) {
    // LDS-staged coalesced bf16 store (wave-private region, stride-72 pad)
    short* eb = ((short*)lds3) + wid * 4608;        // 64 rows x 72
    short* C = (short*)((z == 0) ? Cq : Ck);
#pragma unroll
    for (int i = 0; i < 4; ++i)
#pragma unroll
      for (int r = 0; r < 4; ++r)
#pragma unroll
        for (int j = 0; j < 4; ++j)
          eb[(i * 16 + hi * 4 + r) * 72 + j * 16 + lo] = f2bf(acc[i][j][r]);
#pragma unroll
    for (int p = 0; p < 8; ++p) {
      const short8 v = *(const short8*)&eb[(p * 8 + (lane >> 3)) * 72 + (lane & 7) * 8];
      *(short8*)&C[(size_t)(m0 + wr * 64 + p * 8 + (lane >> 3)) * Dd
                   + n0 + wn * 64 + (lane & 7) * 8] = v;
    }
  } else if (MODE == 2) {
    // LDS-staged coalesced fp32 store, two half-tile passes (wave-private)
    float* fbuf = ((float*)lds3) + wid * 2176;      // 32 rows x 68
    float* C = (float*)Cq;
#pragma unroll
    for (int p = 0; p < 2; ++p) {
#pragma unroll
      for (int ii = 0; ii < 2; ++ii)
#pragma unroll
        for (int r = 0; r < 4; ++r)
#pragma unroll
          for (int j = 0; j < 4; ++j)
            fbuf[(ii * 16 + hi * 4 + r) * 68 + j * 16 + lo] = acc[2 * p + ii][j][r];
#pragma unroll
      for (int q = 0; q < 8; ++q) {
        const float4 v = *(const float4*)&fbuf[(q * 4 + (lane >> 4)) * 68 + (lane & 15) * 4];
        *(float4*)&C[(size_t)(m0 + wr * 64 + p * 32 + q * 4 + (lane >> 4)) * Dd
                     + n0 + wn * 64 + (lane & 15) * 4] = v;
      }
    }
  } else {
    // circular-diagonal reduce into mv[z]
    float red[7][4];
#pragma unroll
    for (int d = 0; d < 7; ++d)
#pragma unroll
      for (int r = 0; r < 4; ++r) red[d][r] = 0.f;
#pragma unroll
    for (int i = 0; i < 4; ++i)
#pragma unroll
      for (int j = 0; j < 4; ++j)
#pragma unroll
        for (int r = 0; r < 4; ++r) red[i - j + 3][r] += acc[i][j][r];

    const int dbase = 127 + (wr * 64 - wn * 64) + 4 * hi - lo;
#pragma unroll
    for (int d = 0; d < 7; ++d)
#pragma unroll
      for (int r = 0; r < 4; ++r)
        atomicAdd(&bins[dbase + 16 * (d - 3) + r], red[d][r]);
    __syncthreads();
    if (tid < 383) {
      float* mv = (float*)Cq;
      const int l = (m0 - n0 + tid - 127) & (Ll - 1);
      atomicAdd(&mv[z * Ll + l], bins[tid]);
    }
  }
}

// ===========================================================================
// prep: z=0 straight cvt WQ->bf16 (+ zero mv); z=1 wtrans WV; z=2 wtrans Wfc
// ===========================================================================
__global__ __launch_bounds__(256) void prep(
    const float* __restrict__ WQ, const float* __restrict__ WV,
    const float* __restrict__ Wfc,
    short* __restrict__ wqb, short* __restrict__ wtv,
    short* __restrict__ wtf, float* __restrict__ mv)
{
  __shared__ float t[32][33];
  const int z = blockIdx.z;
  const int tx = threadIdx.x & 31, ty = threadIdx.x >> 5;
  const int bx = blockIdx.x, by = blockIdx.y;
  if (z == 0) {
#pragma unroll
    for (int s = 0; s < 32; s += 8) {
      const size_t o = (size_t)(by * 32 + ty + s) * 512 + bx * 32 + tx;
      wqb[o] = f2bf(WQ[o]);
    }
    const int fb = by * 16 + bx;
    if (threadIdx.x < 64) mv[fb * 64 + threadIdx.x] = 0.f;
  } else {
    const float* W = (z == 1) ? WV : Wfc;
    short* O = (z == 1) ? wtv : wtf;
#pragma unroll
    for (int s = 0; s < 32; s += 8)
      t[ty + s][tx] = W[(size_t)(by * 32 + ty + s) * 512 + bx * 32 + tx];
    __syncthreads();
#pragma unroll
    for (int s = 0; s < 32; s += 8)
      O[(size_t)(bx * 32 + ty + s) * 512 + by * 32 + tx] = f2bf(t[tx][ty + s]);
  }
}

__global__ __launch_bounds__(1024) void topk_softmax(
    const float* __restrict__ mean_value,
    int* __restrict__ idx_out, float* __restrict__ w_out)
{
  __shared__ float vals[1024];
  __shared__ int   inds[1024];
  __shared__ float bm[1024];
  __shared__ int   topi[TOPK];
  const int t = threadIdx.x;
  float s = 0.f;
  for (int b = 0; b < Bb; ++b) s += mean_value[b * Ll + t];
  bm[t] = s;
  __syncthreads();
  for (int k = 0; k < TOPK; ++k) {
    bool taken = false;
    for (int j = 0; j < k; ++j) taken |= (topi[j] == t);
    vals[t] = taken ? -INFINITY : bm[t];
    inds[t] = t;
    __syncthreads();
    for (int stride = 512; stride > 0; stride >>= 1) {
      if (t < stride) {
        if (vals[t + stride] > vals[t]) { vals[t] = vals[t + stride]; inds[t] = inds[t + stride]; }
      }
      __syncthreads();
    }
    if (t == 0) topi[k] = inds[0];
    __syncthreads();
  }
  if (t < TOPK) idx_out[t] = topi[t];
  if (t < Bb) {
    float wv[TOPK], mx = -INFINITY;
#pragma unroll
    for (int k = 0; k < TOPK; ++k) {
      wv[k] = mean_value[t * Ll + topi[k]] * (1.f / 512.f);
      mx = fmaxf(mx, wv[k]);
    }
    float sum = 0.f;
#pragma unroll
    for (int k = 0; k < TOPK; ++k) { wv[k] = expf(wv[k] - mx); sum += wv[k]; }
#pragma unroll
    for (int k = 0; k < TOPK; ++k) w_out[t * TOPK + k] = wv[k] / sum;
  }
}

// ctx[b][l][c] = sum_k w[b][k] * vs[b][(l+idx_k)%L][c]
__global__ __launch_bounds__(256) void aggregate(
    const short* __restrict__ vs, const float* __restrict__ w,
    const int* __restrict__ idx, short* __restrict__ ctx)
{
  const int b = blockIdx.y;
  __shared__ float ww[8];
  __shared__ int   ii[8];
  if (threadIdx.x < TOPK) { ww[threadIdx.x] = w[b * TOPK + threadIdx.x]; ii[threadIdx.x] = idx[threadIdx.x]; }
  __syncthreads();
  const int l = blockIdx.x * 4 + (threadIdx.x >> 6);
  const int c = (threadIdx.x & 63) * 8;
  const short* vb = vs + (size_t)b * Ll * Dd;
  float a[8] = {};
#pragma unroll
  for (int k = 0; k < TOPK; ++k) {
    const short8 vv = *(const short8*)&vb[(size_t)((l + ii[k]) & (Ll - 1)) * Dd + c];
    const float wk = ww[k];
#pragma unroll
    for (int e = 0; e < 8; ++e) a[e] = fmaf(wk, bf2f(vv[e]), a[e]);
  }
  short8 o;
#pragma unroll
  for (int e = 0; e < 8; ++e) o[e] = f2bf(a[e]);
  *(short8*)&ctx[((size_t)b * Ll + l) * Dd + c] = o;
}

}  // namespace

extern "C" void kernel_launch(void* const* d_in, const int* in_sizes, int n_in,
                              void* d_out, int out_size, void* d_ws, size_t ws_size,
                              hipStream_t stream)
{
  const float* Q   = (const float*)d_in[0];
  const float* K   = (const float*)d_in[1];
  const float* V   = (const float*)d_in[2];
  const float* WQ  = (const float*)d_in[4];
  const float* WK  = (const float*)d_in[5];
  const float* WV  = (const float*)d_in[6];
  const float* Wfc = (const float*)d_in[7];
  float* out = (float*)d_out;

  char* ws = (char*)d_ws;
  const size_t SB = (size_t)Bb * Ll * Dd * sizeof(short);   // 16 MiB
  short* qg   = (short*)(ws);
  short* vsb  = (short*)(ws + 1 * SB);
  short* kb   = (short*)(ws + 2 * SB);
  short* ctxb = (short*)(ws + 3 * SB);
  short* wqb  = (short*)(ws + 4 * SB);
  short* wtv  = wqb + 512 * 512;
  short* wtf  = wtv + 512 * 512;
  short* Gt   = wtf + 512 * 512;
  float* mv   = (float*)(Gt + 512 * 512);
  float* w    = mv + Bb * Ll;
  int*   idx  = (int*)(w + 128);

  // WQ->bf16, wtrans WV/Wfc, zero mv
  prep<<<dim3(16, 16, 3), 256, 0, stream>>>(WQ, WV, Wfc, wqb, wtv, wtf, mv);

  // Gt[j][i] = sum_he WK[j,he]*WQ[i,he]   (= (WQ WK^T)^T, bf16)
  gemm_ring<0><<<dim3(8, 1, 1), 512, 0, stream>>>(
      WK, nullptr, nullptr, wqb, nullptr, nullptr, Gt, nullptr, nullptr);

  // z=0: QG = Q @ Gt^T; z=1: v_s = V @ WV; z=2: kb = bf16(K)
  gemm_ring<0><<<dim3(256, 1, 3), 512, 0, stream>>>(
      Q, V, K, Gt, wtv, nullptr, qg, vsb, kb);

  // mv[b][(t-s)%L] += QG[b,t,:]·kb[b,s,:]
  gemm_ring<1><<<dim3(32, 1, 16), 512, 0, stream>>>(
      qg, nullptr, nullptr, kb, nullptr, nullptr, mv, nullptr, nullptr);

  topk_softmax<<<1, 1024, 0, stream>>>(mv, idx, w);
  aggregate<<<dim3(Ll / 4, Bb), 256, 0, stream>>>(vsb, w, idx, ctxb);

  gemm_ring<2><<<dim3(256, 1, 1), 512, 0, stream>>>(
      ctxb, nullptr, nullptr, wtf, nullptr, nullptr, out, nullptr, nullptr);
}

// Round 6
// 158.812 us; speedup vs baseline: 1.1277x; 1.1277x over previous
//
#include <hip/hip_runtime.h>
#include <math.h>

namespace {

constexpr int Bb = 16;
constexpr int Ll = 1024;
constexpr int Dd = 512;
constexpr int TOPK = 6;
constexpr int Kc = 512;

typedef short  short4v __attribute__((ext_vector_type(4)));
typedef short  short8 __attribute__((ext_vector_type(8)));
typedef float  f32x4  __attribute__((ext_vector_type(4)));

__device__ __forceinline__ short f2bf(float x) {
  unsigned u = __builtin_bit_cast(unsigned, x);
  u += 0x7fffu + ((u >> 16) & 1u);          // RNE
  return (short)(u >> 16);
}
__device__ __forceinline__ float bf2f(short b) {
  unsigned u = ((unsigned)(unsigned short)b) << 16;
  return __builtin_bit_cast(float, u);
}
__device__ __forceinline__ void g2l16(const void* g, void* l) {
  __builtin_amdgcn_global_load_lds(
      (const __attribute__((address_space(1))) unsigned*)g,
      (__attribute__((address_space(3))) unsigned*)l, 16, 0, 0);
}
__device__ __forceinline__ short8 cvt8(float4 a, float4 b) {
  short8 o;
  o[0] = f2bf(a.x); o[1] = f2bf(a.y); o[2] = f2bf(a.z); o[3] = f2bf(a.w);
  o[4] = f2bf(b.x); o[5] = f2bf(b.y); o[6] = f2bf(b.z); o[7] = f2bf(b.w);
  return o;
}

// ===========================================================================
// proj: C[z] = bf16( fp32 A[z] @ WT[z]^T ), z in {Q,K,V}. M=16384, N=K=512.
// BM=128, BN=512 (FULL N -> A read once). 1024 thr, 16 waves (2m x 8n) of
// 64x64. 2-slot LDS dbuf (40 KB/slot). A: fp32 reg-load + cvt + swizzled
// ds_write. B: g2l16 with inverse-swizzled global source. One barrier/K-step.
// LDS unit swizzle: data(row,c8) at unit row*4 + (c8 ^ ((row>>1)&3)).
// ===========================================================================
__global__ __launch_bounds__(1024) void proj_gemm(
    const float* __restrict__ Qf, const float* __restrict__ Kf,
    const float* __restrict__ Vf,
    const short* __restrict__ wq, const short* __restrict__ wk,
    const short* __restrict__ wv,
    short* __restrict__ oq, short* __restrict__ ok, short* __restrict__ ov)
{
  __shared__ short lds[2][20480];        // per slot: A shorts [0,4096), B [4096,20480)

  const int tid = threadIdx.x;
  // bijective XCD chunk swizzle over 384 blocks (chunk = 48)
  const int fb = blockIdx.x;
  const int s  = (fb & 7) * 48 + (fb >> 3);
  const int z  = s / 128;
  const int m0 = (s % 128) * 128;

  const float* Af = (z == 0) ? Qf : (z == 1) ? Kf : Vf;
  const short* Bp = (z == 0) ? wq : (z == 1) ? wk : wv;
  short*       C  = (z == 0) ? oq : (z == 1) ? ok : ov;

  // A staging: thread t -> row = t>>3, quad q = t&7 (4 fp32 cols at q*4)
  const int rowA = tid >> 3, qA = tid & 7;
  const float* gA = Af + (size_t)(m0 + rowA) * Kc + qA * 4;
  const int offA = (rowA * 4 + ((qA >> 1) ^ ((rowA >> 1) & 3))) * 8 + (qA & 1) * 4;

  // B staging: 2 g2l16, units u0 = tid, u1 = 1024 + tid
  const int rB0 = tid >> 2,           c80 = (tid & 3) ^ ((rB0 >> 1) & 3);
  const int rB1 = (1024 + tid) >> 2,  c81 = (tid & 3) ^ ((rB1 >> 1) & 3);
  const short* gB0 = Bp + (size_t)rB0 * Kc + c80 * 8;
  const short* gB1 = Bp + (size_t)rB1 * Kc + c81 * 8;
  const int dB0 = 4096 + tid * 8, dB1 = 4096 + (1024 + tid) * 8;

  // fragments
  const int lane = tid & 63;
  const int wid  = tid >> 6;
  const int wm = wid >> 3, wn = wid & 7;
  const int lo = lane & 15, hi = lane >> 4;
  int aoff[4], boff[4];
#pragma unroll
  for (int i = 0; i < 4; ++i) {
    const int ar = wm * 64 + i * 16 + lo;
    aoff[i] = (ar * 4 + (hi ^ ((ar >> 1) & 3))) * 8;
  }
#pragma unroll
  for (int j = 0; j < 4; ++j) {
    const int br = wn * 64 + j * 16 + lo;
    boff[j] = 4096 + (br * 4 + (hi ^ ((br >> 1) & 3))) * 8;
  }

  f32x4 acc[4][4];
#pragma unroll
  for (int i = 0; i < 4; ++i)
#pragma unroll
    for (int j = 0; j < 4; ++j) acc[i][j] = (f32x4){0.f, 0.f, 0.f, 0.f};

  // prologue: stage k-tile 0 into slot 0
  {
    const float4 v = *(const float4*)(gA);
    g2l16(gB0, &lds[0][dB0]);
    g2l16(gB1, &lds[0][dB1]);
    short4v s4; s4[0] = f2bf(v.x); s4[1] = f2bf(v.y); s4[2] = f2bf(v.z); s4[3] = f2bf(v.w);
    *(short4v*)&lds[0][offA] = s4;
  }
  __syncthreads();

#pragma unroll 1
  for (int t = 0; t < 16; ++t) {
    const int cur = t & 1;
    const short* L = &lds[cur][0];
    short8 af[4], bfr[4];
#pragma unroll
    for (int i = 0; i < 4; ++i) af[i]  = *(const short8*)(L + aoff[i]);
#pragma unroll
    for (int j = 0; j < 4; ++j) bfr[j] = *(const short8*)(L + boff[j]);

    float4 av;
    if (t < 15) {
      const int ke = (t + 1) * 32;
      av = *(const float4*)(gA + ke);
      g2l16(gB0 + ke, &lds[cur ^ 1][dB0]);
      g2l16(gB1 + ke, &lds[cur ^ 1][dB1]);
    }

#pragma unroll
    for (int i = 0; i < 4; ++i)
#pragma unroll
      for (int j = 0; j < 4; ++j)
        acc[i][j] = __builtin_amdgcn_mfma_f32_16x16x32_bf16(af[i], bfr[j], acc[i][j], 0, 0, 0);

    if (t < 15) {
      short4v s4; s4[0] = f2bf(av.x); s4[1] = f2bf(av.y); s4[2] = f2bf(av.z); s4[3] = f2bf(av.w);
      *(short4v*)&lds[cur ^ 1][offA] = s4;
    }
    __syncthreads();
  }

  // epilogue: LDS-bounced coalesced bf16 stores (4 sub-iters of 32 KB)
  short* eb = &lds[0][0];
  const int wid2 = tid >> 6, rem = tid & 63;
  const int rr = rem >> 2, c0 = (rem & 3) * 16;
  const size_t orow = (size_t)(m0 + (wid2 >> 3) * 64) * Dd + (wid2 & 7) * 64 + c0;
#pragma unroll
  for (int i = 0; i < 4; ++i) {
    if (i) __syncthreads();
#pragma unroll
    for (int r = 0; r < 4; ++r)
#pragma unroll
      for (int j = 0; j < 4; ++j)
        eb[wid * 1088 + (hi * 4 + r) * 68 + j * 16 + lo] = f2bf(acc[i][j][r]);
    __syncthreads();
    const short8 v0 = *(const short8*)&eb[wid2 * 1088 + rr * 68 + c0];
    const short8 v1 = *(const short8*)&eb[wid2 * 1088 + rr * 68 + c0 + 8];
    *(short8*)&C[orow + (size_t)(i * 16 + rr) * Dd]     = v0;
    *(short8*)&C[orow + (size_t)(i * 16 + rr) * Dd + 8] = v1;
  }
}

// ===========================================================================
// corr: per batch, mv[z][(m-n)%1024] += q_s[m,:]·k_s[n,:].  BM=BN=256,
// 1024 thr, 16 waves (4m x 4n) of 64x64, 2-slot dbuf (32 KB/slot), g2l16
// swizzled staging, fused 511-diagonal reduction.
// ===========================================================================
__global__ __launch_bounds__(1024) void corr_gemm(
    const short* __restrict__ A, const short* __restrict__ BT,
    float* __restrict__ mv)
{
  __shared__ short lds[2][16384];        // A [0,8192), B [8192,16384)
  __shared__ float bins[512];

  const int tid = threadIdx.x;
  // chunk swizzle, chunk = 32: each XCD gets 2 whole batches (L2 residency)
  const int fb = blockIdx.x;
  const int s  = (fb & 7) * 32 + (fb >> 3);
  const int z  = s >> 4;
  const int m0 = ((s >> 2) & 3) * 256;
  const int n0 = (s & 3) * 256;

  const short* Ab = A  + (size_t)z * Ll * Kc;
  const short* Bp = BT + (size_t)z * Ll * Kc;

  // staging: thread t -> A unit t, B unit t
  const int rS  = tid >> 2;
  const int c8S = (tid & 3) ^ ((rS >> 1) & 3);
  const short* gA = Ab + (size_t)(m0 + rS) * Kc + c8S * 8;
  const short* gB = Bp + (size_t)(n0 + rS) * Kc + c8S * 8;
  const int dA = tid * 8, dB = 8192 + tid * 8;

  const int lane = tid & 63;
  const int wid  = tid >> 6;
  const int wm = wid >> 2, wn = wid & 3;
  const int lo = lane & 15, hi = lane >> 4;
  int aoff[4], boff[4];
#pragma unroll
  for (int i = 0; i < 4; ++i) {
    const int ar = wm * 64 + i * 16 + lo;
    aoff[i] = (ar * 4 + (hi ^ ((ar >> 1) & 3))) * 8;
  }
#pragma unroll
  for (int j = 0; j < 4; ++j) {
    const int br = wn * 64 + j * 16 + lo;
    boff[j] = 8192 + (br * 4 + (hi ^ ((br >> 1) & 3))) * 8;
  }

  if (tid < 512) bins[tid] = 0.f;

  f32x4 acc[4][4];
#pragma unroll
  for (int i = 0; i < 4; ++i)
#pragma unroll
    for (int j = 0; j < 4; ++j) acc[i][j] = (f32x4){0.f, 0.f, 0.f, 0.f};

  g2l16(gA, &lds[0][dA]);
  g2l16(gB, &lds[0][dB]);
  __syncthreads();

#pragma unroll 1
  for (int t = 0; t < 16; ++t) {
    const int cur = t & 1;
    const short* L = &lds[cur][0];
    short8 af[4], bfr[4];
#pragma unroll
    for (int i = 0; i < 4; ++i) af[i]  = *(const short8*)(L + aoff[i]);
#pragma unroll
    for (int j = 0; j < 4; ++j) bfr[j] = *(const short8*)(L + boff[j]);

    if (t < 15) {
      const int ke = (t + 1) * 32;
      g2l16(gA + ke, &lds[cur ^ 1][dA]);
      g2l16(gB + ke, &lds[cur ^ 1][dB]);
    }

#pragma unroll
    for (int i = 0; i < 4; ++i)
#pragma unroll
      for (int j = 0; j < 4; ++j)
        acc[i][j] = __builtin_amdgcn_mfma_f32_16x16x32_bf16(af[i], bfr[j], acc[i][j], 0, 0, 0);
    __syncthreads();
  }

  // diagonal pre-reduce by (i-j, r), then LDS bins, then 511 global atomics
  float red[7][4];
#pragma unroll
  for (int d = 0; d < 7; ++d)
#pragma unroll
    for (int r = 0; r < 4; ++r) red[d][r] = 0.f;
#pragma unroll
  for (int i = 0; i < 4; ++i)
#pragma unroll
    for (int j = 0; j < 4; ++j)
#pragma unroll
      for (int r = 0; r < 4; ++r) red[i - j + 3][r] += acc[i][j][r];

  const int dbase = 255 + (wm - wn) * 64 + 4 * hi - lo;
#pragma unroll
  for (int d = 0; d < 7; ++d)
#pragma unroll
    for (int r = 0; r < 4; ++r)
      atomicAdd(&bins[dbase + 16 * (d - 3) + r], red[d][r]);
  __syncthreads();
  if (tid < 511) {
    const int l = (m0 - n0 + tid - 255) & (Ll - 1);
    atomicAdd(&mv[z * Ll + l], bins[tid]);
  }
}

// ===========================================================================
// fc: out_fp32 = ctx_bf16 @ WfcT^T.  BM=128, BN=256, 512 thr, 8 waves
// (2m x 4n) of 64x64, 2-slot dbuf (24 KB/slot).
// ===========================================================================
__global__ __launch_bounds__(512) void fc_gemm(
    const short* __restrict__ A, const short* __restrict__ BT,
    float* __restrict__ C)
{
  __shared__ short lds[2][12288];        // A [0,4096), B [4096,12288)

  const int tid = threadIdx.x;
  const int fb = blockIdx.x;             // 256 blocks, chunk = 32
  const int s  = (fb & 7) * 32 + (fb >> 3);
  const int m0 = (s >> 1) * 128;
  const int n0 = (s & 1) * 256;

  // A: 512 units, thread t -> unit t.  B: 1024 units, units t and 512+t.
  const int rA  = tid >> 2;
  const int c8A = (tid & 3) ^ ((rA >> 1) & 3);
  const short* gA = A + (size_t)(m0 + rA) * Kc + c8A * 8;
  const int dA = tid * 8;
  const int rB0 = tid >> 2,          c8B0 = (tid & 3) ^ ((rB0 >> 1) & 3);
  const int rB1 = (512 + tid) >> 2,  c8B1 = (tid & 3) ^ ((rB1 >> 1) & 3);
  const short* gB0 = BT + (size_t)(n0 + rB0) * Kc + c8B0 * 8;
  const short* gB1 = BT + (size_t)(n0 + rB1) * Kc + c8B1 * 8;
  const int dB0 = 4096 + tid * 8, dB1 = 4096 + (512 + tid) * 8;

  const int lane = tid & 63;
  const int wid  = tid >> 6;
  const int wm = wid >> 2, wn = wid & 3;
  const int lo = lane & 15, hi = lane >> 4;
  int aoff[4], boff[4];
#pragma unroll
  for (int i = 0; i < 4; ++i) {
    const int ar = wm * 64 + i * 16 + lo;
    aoff[i] = (ar * 4 + (hi ^ ((ar >> 1) & 3))) * 8;
  }
#pragma unroll
  for (int j = 0; j < 4; ++j) {
    const int br = wn * 64 + j * 16 + lo;
    boff[j] = 4096 + (br * 4 + (hi ^ ((br >> 1) & 3))) * 8;
  }

  f32x4 acc[4][4];
#pragma unroll
  for (int i = 0; i < 4; ++i)
#pragma unroll
    for (int j = 0; j < 4; ++j) acc[i][j] = (f32x4){0.f, 0.f, 0.f, 0.f};

  g2l16(gA,  &lds[0][dA]);
  g2l16(gB0, &lds[0][dB0]);
  g2l16(gB1, &lds[0][dB1]);
  __syncthreads();

#pragma unroll 1
  for (int t = 0; t < 16; ++t) {
    const int cur = t & 1;
    const short* L = &lds[cur][0];
    short8 af[4], bfr[4];
#pragma unroll
    for (int i = 0; i < 4; ++i) af[i]  = *(const short8*)(L + aoff[i]);
#pragma unroll
    for (int j = 0; j < 4; ++j) bfr[j] = *(const short8*)(L + boff[j]);

    if (t < 15) {
      const int ke = (t + 1) * 32;
      g2l16(gA  + ke, &lds[cur ^ 1][dA]);
      g2l16(gB0 + ke, &lds[cur ^ 1][dB0]);
      g2l16(gB1 + ke, &lds[cur ^ 1][dB1]);
    }

#pragma unroll
    for (int i = 0; i < 4; ++i)
#pragma unroll
      for (int j = 0; j < 4; ++j)
        acc[i][j] = __builtin_amdgcn_mfma_f32_16x16x32_bf16(af[i], bfr[j], acc[i][j], 0, 0, 0);
    __syncthreads();
  }

#pragma unroll
  for (int i = 0; i < 4; ++i)
#pragma unroll
    for (int r = 0; r < 4; ++r) {
      const size_t row = m0 + wm * 64 + i * 16 + hi * 4 + r;
#pragma unroll
      for (int j = 0; j < 4; ++j)
        C[row * Dd + n0 + wn * 64 + j * 16 + lo] = acc[i][j][r];
    }
}

// W[512][512] fp32 -> WT bf16 (transposed), 4 weights; z==0 also zeroes mv
__global__ __launch_bounds__(256) void prep(
    const float* __restrict__ w0, const float* __restrict__ w1,
    const float* __restrict__ w2, const float* __restrict__ w3,
    short* __restrict__ o0, short* __restrict__ o1,
    short* __restrict__ o2, short* __restrict__ o3,
    float* __restrict__ mv)
{
  const int z = blockIdx.z;
  const float* W = (z == 0) ? w0 : (z == 1) ? w1 : (z == 2) ? w2 : w3;
  short* O = (z == 0) ? o0 : (z == 1) ? o1 : (z == 2) ? o2 : o3;
  __shared__ float t[32][33];
  const int tx = threadIdx.x & 31, ty = threadIdx.x >> 5;
  const int bx = blockIdx.x, by = blockIdx.y;
#pragma unroll
  for (int s = 0; s < 32; s += 8)
    t[ty + s][tx] = W[(size_t)(by * 32 + ty + s) * 512 + bx * 32 + tx];
  __syncthreads();
#pragma unroll
  for (int s = 0; s < 32; s += 8)
    O[(size_t)(bx * 32 + ty + s) * 512 + by * 32 + tx] = f2bf(t[tx][ty + s]);
  if (z == 0 && threadIdx.x < 64) {
    const int fb = by * 16 + bx;
    mv[fb * 64 + threadIdx.x] = 0.f;
  }
}

__global__ __launch_bounds__(1024) void topk_softmax(
    const float* __restrict__ mean_value,
    int* __restrict__ idx_out, float* __restrict__ w_out)
{
  __shared__ float vals[1024];
  __shared__ int   inds[1024];
  __shared__ float bm[1024];
  __shared__ int   topi[TOPK];
  const int t = threadIdx.x;
  float s = 0.f;
  for (int b = 0; b < Bb; ++b) s += mean_value[b * Ll + t];
  bm[t] = s;
  __syncthreads();
  for (int k = 0; k < TOPK; ++k) {
    bool taken = false;
    for (int j = 0; j < k; ++j) taken |= (topi[j] == t);
    vals[t] = taken ? -INFINITY : bm[t];
    inds[t] = t;
    __syncthreads();
    for (int stride = 512; stride > 0; stride >>= 1) {
      if (t < stride) {
        if (vals[t + stride] > vals[t]) { vals[t] = vals[t + stride]; inds[t] = inds[t + stride]; }
      }
      __syncthreads();
    }
    if (t == 0) topi[k] = inds[0];
    __syncthreads();
  }
  if (t < TOPK) idx_out[t] = topi[t];
  if (t < Bb) {
    float wv[TOPK], mx = -INFINITY;
#pragma unroll
    for (int k = 0; k < TOPK; ++k) {
      wv[k] = mean_value[t * Ll + topi[k]] * (1.f / 512.f);
      mx = fmaxf(mx, wv[k]);
    }
    float sum = 0.f;
#pragma unroll
    for (int k = 0; k < TOPK; ++k) { wv[k] = expf(wv[k] - mx); sum += wv[k]; }
#pragma unroll
    for (int k = 0; k < TOPK; ++k) w_out[t * TOPK + k] = wv[k] / sum;
  }
}

// ctx[b][l][c] = sum_k w[b][k] * vs[b][(l+idx_k)%L][c]
__global__ __launch_bounds__(256) void aggregate(
    const short* __restrict__ vs, const float* __restrict__ w,
    const int* __restrict__ idx, short* __restrict__ ctx)
{
  const int b = blockIdx.y;
  __shared__ float ww[8];
  __shared__ int   ii[8];
  if (threadIdx.x < TOPK) { ww[threadIdx.x] = w[b * TOPK + threadIdx.x]; ii[threadIdx.x] = idx[threadIdx.x]; }
  __syncthreads();
  const int l = blockIdx.x * 4 + (threadIdx.x >> 6);
  const int c = (threadIdx.x & 63) * 8;
  const short* vb = vs + (size_t)b * Ll * Dd;
  float a[8] = {};
#pragma unroll
  for (int k = 0; k < TOPK; ++k) {
    const short8 vv = *(const short8*)&vb[(size_t)((l + ii[k]) & (Ll - 1)) * Dd + c];
    const float wk = ww[k];
#pragma unroll
    for (int e = 0; e < 8; ++e) a[e] = fmaf(wk, bf2f(vv[e]), a[e]);
  }
  short8 o;
#pragma unroll
  for (int e = 0; e < 8; ++e) o[e] = f2bf(a[e]);
  *(short8*)&ctx[((size_t)b * Ll + l) * Dd + c] = o;
}

}  // namespace

extern "C" void kernel_launch(void* const* d_in, const int* in_sizes, int n_in,
                              void* d_out, int out_size, void* d_ws, size_t ws_size,
                              hipStream_t stream)
{
  const float* Q   = (const float*)d_in[0];
  const float* K   = (const float*)d_in[1];
  const float* V   = (const float*)d_in[2];
  const float* WQ  = (const float*)d_in[4];
  const float* WK  = (const float*)d_in[5];
  const float* WV  = (const float*)d_in[6];
  const float* Wfc = (const float*)d_in[7];
  float* out = (float*)d_out;

  char* ws = (char*)d_ws;
  const size_t SB = (size_t)Bb * Ll * Dd * sizeof(short);   // 16 MiB
  short* qsb  = (short*)(ws);
  short* ksb  = (short*)(ws + 1 * SB);
  short* vsb  = (short*)(ws + 2 * SB);
  short* ctxb = (short*)(ws + 3 * SB);
  short* wtq  = (short*)(ws + 4 * SB);
  short* wtk  = wtq + 512 * 512;
  short* wtv  = wtk + 512 * 512;
  short* wtf  = wtv + 512 * 512;
  float* mv   = (float*)(wtf + 512 * 512);
  float* w    = mv + Bb * Ll;
  int*   idx  = (int*)(w + 128);

  prep<<<dim3(16, 16, 4), 256, 0, stream>>>(WQ, WK, WV, Wfc, wtq, wtk, wtv, wtf, mv);

  proj_gemm<<<dim3(384, 1, 1), 1024, 0, stream>>>(Q, K, V, wtq, wtk, wtv, qsb, ksb, vsb);

  corr_gemm<<<dim3(256, 1, 1), 1024, 0, stream>>>(qsb, ksb, mv);

  topk_softmax<<<1, 1024, 0, stream>>>(mv, idx, w);
  aggregate<<<dim3(Ll / 4, Bb), 256, 0, stream>>>(vsb, w, idx, ctxb);

  fc_gemm<<<dim3(256, 1, 1), 512, 0, stream>>>(ctxb, wtf, out);
}

// Round 7
// 138.353 us; speedup vs baseline: 1.2945x; 1.1479x over previous
//
#include <hip/hip_runtime.h>
#include <math.h>

namespace {

constexpr int Bb = 16;
constexpr int Ll = 1024;
constexpr int Dd = 512;
constexpr int TOPK = 6;
constexpr int Kc = 512;

typedef short  short8 __attribute__((ext_vector_type(8)));
typedef float  f32x4  __attribute__((ext_vector_type(4)));

__device__ __forceinline__ short f2bf(float x) {
  unsigned u = __builtin_bit_cast(unsigned, x);
  u += 0x7fffu + ((u >> 16) & 1u);          // RNE
  return (short)(u >> 16);
}
__device__ __forceinline__ float bf2f(short b) {
  unsigned u = ((unsigned)(unsigned short)b) << 16;
  return __builtin_bit_cast(float, u);
}
__device__ __forceinline__ void g2l16(const void* g, void* l) {
  __builtin_amdgcn_global_load_lds(
      (const __attribute__((address_space(1))) unsigned*)g,
      (__attribute__((address_space(3))) unsigned*)l, 16, 0, 0);
}
__device__ __forceinline__ short8 cvt8(float4 a, float4 b) {
  short8 o;
  o[0] = f2bf(a.x); o[1] = f2bf(a.y); o[2] = f2bf(a.z); o[3] = f2bf(a.w);
  o[4] = f2bf(b.x); o[5] = f2bf(b.y); o[6] = f2bf(b.z); o[7] = f2bf(b.w);
  return o;
}

#define BARRIER() do { asm volatile("" ::: "memory"); \
    __builtin_amdgcn_s_barrier(); \
    asm volatile("" ::: "memory"); } while (0)
#define VMCNT8() asm volatile("s_waitcnt vmcnt(8)" ::: "memory")
#define VMCNT4() asm volatile("s_waitcnt vmcnt(4)" ::: "memory")
#define VMCNT0() asm volatile("s_waitcnt vmcnt(0)" ::: "memory")
#define LGKM0()  do { asm volatile("s_waitcnt lgkmcnt(0)" ::: "memory"); \
    __builtin_amdgcn_sched_barrier(0); } while (0)

// ===========================================================================
// NT GEMM, 128x128 tile, BK=64 (8 K-steps), 256 thr (4 waves, 2m x 2n of
// 64x64), depth-2 LDS ring with counted entry-vmcnt, XOR-swizzled LDS.
// C[m][n] = sum_k A[m][k] * BT[n][k], K = N = 512.
// MODE 0: tiny — A,B bf16; C bf16.   z: 0 = Gt, 1 = Ht       (32 blocks)
// MODE 1: front — A fp32 (T14 split-stage + cvt), B bf16; C bf16.
//         z: 0 = T = Q@Gt^T, 1 = U = V@Ht^T                  (512 x 2 blocks)
// MODE 2: corr — A bf16 (=T, batch z), B fp32 (=K, batch z, split-stage);
//         fused circular-diagonal reduce into mv[z]          (1024 blocks)
// LDS swizzle: data(row, c8) stored at unit row*8 + (c8 ^ (row&7)); 16B units.
// ===========================================================================
template<int MODE>
__global__ __launch_bounds__(256) void g64(
    const void* __restrict__ A0, const void* __restrict__ A1,
    const short* __restrict__ B0, const short* __restrict__ B1,
    void* __restrict__ C0, void* __restrict__ C1)
{
  __shared__ short lds[2][16384];   // per buf: A [0,8192), B [8192,16384)
  __shared__ float bins[256];

  const int tid = threadIdx.x;
  int z, m0, n0;
  if (MODE == 0) {
    z = blockIdx.x >> 4;
    const int s = blockIdx.x & 15;
    m0 = (s >> 2) * 128;  n0 = (s & 3) * 128;
  } else if (MODE == 1) {
    z = blockIdx.z;
    const int fb = blockIdx.x;                 // 512, XCD chunk = 64
    const int s  = (fb & 7) * 64 + (fb >> 3);
    m0 = (s >> 2) * 128;  n0 = (s & 3) * 128;
  } else {
    const int fb = blockIdx.x;                 // 1024, XCD chunk = 128
    const int s  = (fb & 7) * 128 + (fb >> 3);
    z  = s >> 6;
    m0 = ((s >> 3) & 7) * 128;  n0 = (s & 7) * 128;
  }

  // ---- staging source pointers (swizzled: c8S constant per thread) ----
  const int rS  = tid >> 3;                    // 0..31 (row within 32-row group)
  const int c8S = (tid & 7) ^ (rS & 7);        // source 16B-slot
  const short* Ga = nullptr;  const float* Fa = nullptr;
  const short* Gb = nullptr;  const float* Fb = nullptr;
  if (MODE == 0) {
    Ga = (const short*)(z ? A1 : A0) + (size_t)(m0 + rS) * Kc + c8S * 8;
    Gb = (z ? B1 : B0) + (size_t)(n0 + rS) * Kc + c8S * 8;
  } else if (MODE == 1) {
    Fa = (const float*)(z ? A1 : A0) + (size_t)(m0 + rS) * Kc + c8S * 8;
    Gb = (z ? B1 : B0) + (size_t)(n0 + rS) * Kc + c8S * 8;
  } else {
    Ga = (const short*)A0 + (size_t)z * Ll * Kc + (size_t)(m0 + rS) * Kc + c8S * 8;
    Fb = (const float*)A1 + (size_t)z * Ll * Kc + (size_t)(n0 + rS) * Kc + c8S * 8;
  }

  // ---- fragment read offsets (per i and k-slice ks) ----
  const int lane = tid & 63;
  const int wid  = tid >> 6;
  const int wr = wid >> 1, wn = wid & 1;
  const int lo = lane & 15, hi = lane >> 4;
  int aoff[2][4], boff[2][4];
#pragma unroll
  for (int i = 0; i < 4; ++i) {
    const int ar = wr * 64 + i * 16 + lo;
    const int br = wn * 64 + i * 16 + lo;
#pragma unroll
    for (int ks = 0; ks < 2; ++ks) {
      aoff[ks][i] = (ar * 8 + ((ks * 4 + hi) ^ (ar & 7))) * 8;
      boff[ks][i] = 8192 + (br * 8 + ((ks * 4 + hi) ^ (br & 7))) * 8;
    }
  }

  if (MODE == 2) bins[tid] = 0.f;

  f32x4 acc[4][4];
#pragma unroll
  for (int i = 0; i < 4; ++i)
#pragma unroll
    for (int j = 0; j < 4; ++j) acc[i][j] = (f32x4){0.f, 0.f, 0.f, 0.f};

  // ---- staging helpers (kt = K-tile index, 64 cols each) ----
#define SG_A(buf, kt) do { _Pragma("unroll") \
    for (int i_ = 0; i_ < 4; ++i_) \
      g2l16(Ga + (size_t)i_ * 32 * Kc + (kt) * 64, &lds[buf][(i_ * 256 + tid) * 8]); } while (0)
#define SG_B(buf, kt) do { _Pragma("unroll") \
    for (int i_ = 0; i_ < 4; ++i_) \
      g2l16(Gb + (size_t)i_ * 32 * Kc + (kt) * 64, &lds[buf][8192 + (i_ * 256 + tid) * 8]); } while (0)
#define LD_F(eV, F, kt) do { _Pragma("unroll") \
    for (int i_ = 0; i_ < 4; ++i_) { \
      eV[2 * i_]     = *(const float4*)((F) + (size_t)i_ * 32 * Kc + (kt) * 64); \
      eV[2 * i_ + 1] = *(const float4*)((F) + (size_t)i_ * 32 * Kc + (kt) * 64 + 4); } } while (0)
#define WR_F(buf, opb, eV) do { _Pragma("unroll") \
    for (int i_ = 0; i_ < 4; ++i_) \
      *(short8*)&lds[buf][(opb) + (i_ * 256 + tid) * 8] = cvt8(eV[2 * i_], eV[2 * i_ + 1]); } while (0)

  // ---- prologue: tile0 -> buf0, tile1 -> buf1 ----
  {
    float4 e[8];
    if (MODE == 1) {
      SG_B(0, 0); LD_F(e, Fa, 0); WR_F(0, 0, e);
      SG_B(1, 1); LD_F(e, Fa, 1); WR_F(1, 0, e);
    } else if (MODE == 2) {
      SG_A(0, 0); LD_F(e, Fb, 0); WR_F(0, 8192, e);
      SG_A(1, 1); LD_F(e, Fb, 1); WR_F(1, 8192, e);
    } else {
      SG_A(0, 0); SG_B(0, 0);
      SG_A(1, 1); SG_B(1, 1);
    }
  }

  int cur = 0;
#pragma unroll 1
  for (int t = 0; t < 8; ++t) {
    if (t == 7)            VMCNT0();
    else if (MODE == 0)    VMCNT8();
    else                   VMCNT4();
    LGKM0();
    BARRIER();

    const short* L = lds[cur];
    const bool pf = (t < 6);
    float4 e[8];

    short8 af[4], bq[4];
#pragma unroll
    for (int i = 0; i < 4; ++i) af[i] = *(const short8*)(L + aoff[0][i]);
#pragma unroll
    for (int j = 0; j < 4; ++j) bq[j] = *(const short8*)(L + boff[0][j]);
    if (pf && MODE == 1) LD_F(e, Fa, t + 2);
    if (pf && MODE == 2) LD_F(e, Fb, t + 2);
#pragma unroll
    for (int i = 0; i < 4; ++i)
#pragma unroll
      for (int j = 0; j < 4; ++j)
        acc[i][j] = __builtin_amdgcn_mfma_f32_16x16x32_bf16(af[i], bq[j], acc[i][j], 0, 0, 0);
#pragma unroll
    for (int i = 0; i < 4; ++i) af[i] = *(const short8*)(L + aoff[1][i]);
#pragma unroll
    for (int j = 0; j < 4; ++j) bq[j] = *(const short8*)(L + boff[1][j]);
#pragma unroll
    for (int i = 0; i < 4; ++i)
#pragma unroll
      for (int j = 0; j < 4; ++j)
        acc[i][j] = __builtin_amdgcn_mfma_f32_16x16x32_bf16(af[i], bq[j], acc[i][j], 0, 0, 0);

    BARRIER();   // all waves done reading buf cur -> safe to overwrite

    if (pf) {
      if (MODE == 1)      { SG_B(cur, t + 2); WR_F(cur, 0, e); }
      else if (MODE == 2) { SG_A(cur, t + 2); WR_F(cur, 8192, e); }
      else                { SG_A(cur, t + 2); SG_B(cur, t + 2); }
    }
    cur ^= 1;
  }
#undef SG_A
#undef SG_B
#undef LD_F
#undef WR_F

  // ---- epilogue ----
  if (MODE != 2) {
    short* C = (short*)(MODE == 0 ? (z ? C1 : C0) : (z ? C1 : C0));
#pragma unroll
    for (int i = 0; i < 4; ++i)
#pragma unroll
      for (int r = 0; r < 4; ++r) {
        const size_t row = m0 + wr * 64 + i * 16 + hi * 4 + r;
#pragma unroll
        for (int j = 0; j < 4; ++j)
          C[row * Dd + n0 + wn * 64 + j * 16 + lo] = f2bf(acc[i][j][r]);
      }
  } else {
    // circular-diagonal reduce: register pre-reduce by (i-j, r) -> LDS bins
    float red[7][4];
#pragma unroll
    for (int d = 0; d < 7; ++d)
#pragma unroll
      for (int r = 0; r < 4; ++r) red[d][r] = 0.f;
#pragma unroll
    for (int i = 0; i < 4; ++i)
#pragma unroll
      for (int j = 0; j < 4; ++j)
#pragma unroll
        for (int r = 0; r < 4; ++r) red[i - j + 3][r] += acc[i][j][r];

    const int dbase = 127 + (wr - wn) * 64 + 4 * hi - lo;
#pragma unroll
    for (int d = 0; d < 7; ++d)
#pragma unroll
      for (int r = 0; r < 4; ++r)
        atomicAdd(&bins[dbase + 16 * (d - 3) + r], red[d][r]);
    __syncthreads();
    if (tid < 255) {
      float* mv = (float*)C0;
      const int l = (m0 - n0 + tid - 127) & (Ll - 1);
      atomicAdd(&mv[z * Ll + l], bins[tid]);
    }
  }
}

// ===========================================================================
// prep: z in {0,1,2}: straight fp32->bf16 cvt of WQ/WK/WV (row layout kept);
// z==3: transposed cvt of Wfc (wtf[n][e] = Wfc[e][n]).  z==0 zeroes mv.
// ===========================================================================
__global__ __launch_bounds__(256) void prep(
    const float* __restrict__ WQ, const float* __restrict__ WK,
    const float* __restrict__ WV, const float* __restrict__ Wfc,
    short* __restrict__ wqb, short* __restrict__ wkb,
    short* __restrict__ wvb, short* __restrict__ wtf,
    float* __restrict__ mv)
{
  const int z = blockIdx.z;
  const int tx = threadIdx.x & 31, ty = threadIdx.x >> 5;
  const int bx = blockIdx.x, by = blockIdx.y;
  if (z < 3) {
    const float* W = (z == 0) ? WQ : (z == 1) ? WK : WV;
    short* O = (z == 0) ? wqb : (z == 1) ? wkb : wvb;
#pragma unroll
    for (int s = 0; s < 32; s += 8) {
      const size_t o = (size_t)(by * 32 + ty + s) * 512 + bx * 32 + tx;
      O[o] = f2bf(W[o]);
    }
    if (z == 0 && threadIdx.x < 64) {
      const int fb = by * 16 + bx;
      mv[fb * 64 + threadIdx.x] = 0.f;
    }
  } else {
    __shared__ float t[32][33];
#pragma unroll
    for (int s = 0; s < 32; s += 8)
      t[ty + s][tx] = Wfc[(size_t)(by * 32 + ty + s) * 512 + bx * 32 + tx];
    __syncthreads();
#pragma unroll
    for (int s = 0; s < 32; s += 8)
      wtf[(size_t)(bx * 32 + ty + s) * 512 + by * 32 + tx] = f2bf(t[tx][ty + s]);
  }
}

__global__ __launch_bounds__(1024) void topk_softmax(
    const float* __restrict__ mean_value,
    int* __restrict__ idx_out, float* __restrict__ w_out)
{
  __shared__ float vals[1024];
  __shared__ int   inds[1024];
  __shared__ float bm[1024];
  __shared__ int   topi[TOPK];
  const int t = threadIdx.x;
  float s = 0.f;
  for (int b = 0; b < Bb; ++b) s += mean_value[b * Ll + t];
  bm[t] = s;
  __syncthreads();
  for (int k = 0; k < TOPK; ++k) {
    bool taken = false;
    for (int j = 0; j < k; ++j) taken |= (topi[j] == t);
    vals[t] = taken ? -INFINITY : bm[t];
    inds[t] = t;
    __syncthreads();
    for (int stride = 512; stride > 0; stride >>= 1) {
      if (t < stride) {
        if (vals[t + stride] > vals[t]) { vals[t] = vals[t + stride]; inds[t] = inds[t + stride]; }
      }
      __syncthreads();
    }
    if (t == 0) topi[k] = inds[0];
    __syncthreads();
  }
  if (t < TOPK) idx_out[t] = topi[t];
  if (t < Bb) {
    float wv[TOPK], mx = -INFINITY;
#pragma unroll
    for (int k = 0; k < TOPK; ++k) {
      wv[k] = mean_value[t * Ll + topi[k]] * (1.f / 512.f);
      mx = fmaxf(mx, wv[k]);
    }
    float sum = 0.f;
#pragma unroll
    for (int k = 0; k < TOPK; ++k) { wv[k] = expf(wv[k] - mx); sum += wv[k]; }
#pragma unroll
    for (int k = 0; k < TOPK; ++k) w_out[t * TOPK + k] = wv[k] / sum;
  }
}

// out[b][l][c] = sum_k w[b][k] * bf2f(U[b][(l+idx_k)%L][c])   (fp32 out)
__global__ __launch_bounds__(256) void gather_out(
    const short* __restrict__ U, const float* __restrict__ w,
    const int* __restrict__ idx, float* __restrict__ out)
{
  const int b = blockIdx.y;
  __shared__ float ww[8];
  __shared__ int   ii[8];
  if (threadIdx.x < TOPK) { ww[threadIdx.x] = w[b * TOPK + threadIdx.x]; ii[threadIdx.x] = idx[threadIdx.x]; }
  __syncthreads();
  const int l = blockIdx.x * 4 + (threadIdx.x >> 6);
  const int c = (threadIdx.x & 63) * 8;
  const short* ub = U + (size_t)b * Ll * Dd;
  float a[8] = {};
#pragma unroll
  for (int k = 0; k < TOPK; ++k) {
    const short8 vv = *(const short8*)&ub[(size_t)((l + ii[k]) & (Ll - 1)) * Dd + c];
    const float wk = ww[k];
#pragma unroll
    for (int e = 0; e < 8; ++e) a[e] = fmaf(wk, bf2f(vv[e]), a[e]);
  }
  float* op = &out[((size_t)b * Ll + l) * Dd + c];
  *(float4*)op       = make_float4(a[0], a[1], a[2], a[3]);
  *(float4*)(op + 4) = make_float4(a[4], a[5], a[6], a[7]);
}

}  // namespace

extern "C" void kernel_launch(void* const* d_in, const int* in_sizes, int n_in,
                              void* d_out, int out_size, void* d_ws, size_t ws_size,
                              hipStream_t stream)
{
  const float* Q   = (const float*)d_in[0];
  const float* K   = (const float*)d_in[1];
  const float* V   = (const float*)d_in[2];
  const float* WQ  = (const float*)d_in[4];
  const float* WK  = (const float*)d_in[5];
  const float* WV  = (const float*)d_in[6];
  const float* Wfc = (const float*)d_in[7];
  float* out = (float*)d_out;

  char* ws = (char*)d_ws;
  const size_t SB = (size_t)Bb * Ll * Dd * sizeof(short);   // 16 MiB
  short* T    = (short*)(ws);
  short* U    = (short*)(ws + 1 * SB);
  short* wqb  = (short*)(ws + 2 * SB);
  short* wkb  = wqb + 512 * 512;
  short* wvb  = wkb + 512 * 512;
  short* wtf  = wvb + 512 * 512;
  short* Gt   = wtf + 512 * 512;
  short* Ht   = Gt  + 512 * 512;
  float* mv   = (float*)(Ht + 512 * 512);
  float* w    = mv + Bb * Ll;
  int*   idx  = (int*)(w + 128);

  // weights -> bf16 (wqb/wkb/wvb straight, wtf = Wfc^T), zero mv
  prep<<<dim3(16, 16, 4), 256, 0, stream>>>(WQ, WK, WV, Wfc, wqb, wkb, wvb, wtf, mv);

  // Gt[n][k] = sum_e Wk[n][e]*Wq[k][e] ; Ht[n][k] = sum_e Wfc[e][n]*Wv[k][e]
  g64<0><<<32, 256, 0, stream>>>(wkb, wtf, wqb, wvb, Gt, Ht);

  // T = bf16(Q @ Gt^T) ; U = bf16(V @ Ht^T)
  g64<1><<<dim3(512, 1, 2), 256, 0, stream>>>(Q, V, Gt, Ht, T, U);

  // mv[b][(m-n)%L] += T[b,m,:] · bf16(K[b,n,:])
  g64<2><<<1024, 256, 0, stream>>>(T, K, nullptr, nullptr, mv, nullptr);

  topk_softmax<<<1, 1024, 0, stream>>>(mv, idx, w);

  // out[b,l,:] = sum_k w_k * U[b,(l+d_k)%L,:]
  gather_out<<<dim3(Ll / 4, Bb), 256, 0, stream>>>(U, w, idx, out);
}